// Round 16
// baseline (1261.082 us; speedup 1.0000x reference)
//
#include <hip/hip_runtime.h>

// ---------------------------------------------------------------------------
// ConditionalRealNVP on MI355X.
// Layer-invariant ctx-part of GEMM1 hoisted into ONE 8192x8192x3072 GEMM.
// Big GEMM (BN=256): r13 template (one barrier/phase, hoisted phase-B reads,
// counted vmcnt gate once per K-tile, 4-half-slot ring).
// GEMM2/3 (BN=128): ROUND-16 single-phase K-tiles over a 6-half-slot (3-tile)
// ring (144KB LDS): per K-tile {16 ds_reads, stage tile T+2 (6 loads), lgkm0,
// 32 MFMA, gate vmcnt(6)/(0), BAR} — 1 barrier + 1 lgkm + 1 gate per K-tile.
// WAR safe: stage targets tile T-1's slots, read-complete block-wide before
// BAR(T-1) (lgkm0 precedes it), stage issues after BAR(T-1).
// GEMM4: split-K=2 + fused-sum epilogue (r14).
// ---------------------------------------------------------------------------

#define L_LAYERS 8
#define DDIM     256
#define HDIM     1024
#define BROWS    8192
#define ADIM     128          // D/2
#define BDIM_    128          // D - A
#define INDIM    3200         // A + 3*H
#define CTEDIM   3072         // 3*H
#define CLIPV    3.0f

typedef _Float16 f16x8 __attribute__((ext_vector_type(8)));
typedef _Float16 f16x4 __attribute__((ext_vector_type(4)));
typedef float    f32x4 __attribute__((ext_vector_type(4)));

__device__ __forceinline__ void async_copy16(const _Float16* g, _Float16* s) {
    __builtin_amdgcn_global_load_lds((const __attribute__((address_space(1))) void*)g,
                                     (__attribute__((address_space(3))) void*)s,
                                     16, 0, 0);
}

// ---------------------------------------------------------------------------
// 256xBN template GEMM: C = act(A @ Bt^T + bias)
// BN=256: r13 two-phase loop.  BN=128: r16 single-phase loop, 3-tile ring.
// MODE 0: raw f16 store.  MODE 1: bias + silu -> f16.
// ---------------------------------------------------------------------------
template <int MODE, int BN>
__global__ __launch_bounds__(512, 2)
void gemm8p(const _Float16* __restrict__ A, int lda,
            const _Float16* __restrict__ Bt, int ldb,
            const float* __restrict__ bias,
            _Float16* __restrict__ C, int ldc,
            int K, int gx, int RC, int rr)
{
    constexpr int MR     = (BN == 256) ? 8 : 4;    // M fragments per wave
    constexpr int NSLOT  = (BN == 256) ? 4 : 6;    // half-slots in ring
    constexpr int BSLOT  = BN * 32;                // f16 per B half-slot
    constexpr int BSLOTB = BN * 64;                // bytes per B half-slot
    __shared__ __attribute__((aligned(16))) _Float16 lds[NSLOT * 8192 + NSLOT * BSLOT];

    const int tid  = threadIdx.x;
    const int w    = tid >> 6, lane = tid & 63;

    // ---- 2-D XCD region swizzle ----
    const int bid = blockIdx.x;
    const int xcd = bid & 7, idx = bid >> 3;
    const int rpx = gx / RC;
    const int by  = (xcd / rpx) * rr + idx / RC;
    const int bx  = (xcd % rpx) * RC + idx % RC;
    const int m0  = by << 8, n0 = bx * BN;

    const int NT = K >> 6;   // K-tiles; NT >= 4

    const int srow = tid >> 2;
    const int srcq = ((tid & 3) ^ ((tid >> 3) & 3)) * 8;
    const _Float16* gA = A  + (size_t)(m0 + srow) * lda + srcq;
    const _Float16* gB = Bt + (size_t)(n0 + srow) * ldb + srcq;
    const size_t a128 = (size_t)128 * lda;
    const size_t b128 = (size_t)128 * ldb;
    _Float16* ldsA = lds + w * 512;                    // wave-uniform bases
    _Float16* ldsB = lds + NSLOT * 8192 + w * 512;

    f32x4 acc[MR][4];
#pragma unroll
    for (int i = 0; i < MR; ++i)
#pragma unroll
        for (int j = 0; j < 4; ++j) acc[i][j] = (f32x4){0.f, 0.f, 0.f, 0.f};

    const int qsw = ((lane & 15) >> 1) & 3;
    const int q16 = ((lane >> 4) ^ qsw) << 4;
    const int rA0 = (BN == 256) ? ((w >> 2) * 128 + (lane & 15))
                                : ((w >> 1) * 64  + (lane & 15));
    const int rB  = (BN == 256) ? ((w & 3) * 64 + (lane & 15))
                                : ((w & 1) * 64 + (lane & 15));
    const char* ldsArd = (const char*)lds + (rA0 * 64 + q16);
    const char* ldsBrd = (const char*)lds + NSLOT * 16384 + (rB * 64 + q16);

#define LGKM0() do { asm volatile("s_waitcnt lgkmcnt(0)" ::: "memory");        \
        __builtin_amdgcn_sched_barrier(0); } while (0)

    if constexpr (BN == 256) {
        // ================= r13 two-phase loop (4-half-slot ring) ===========
#define STG(t_, kh_) do { if ((t_) < NT) {                                 \
        const _Float16* sa_ = gA + (size_t)(t_) * 64 + (kh_) * 32;         \
        const _Float16* sb_ = gB + (size_t)(t_) * 64 + (kh_) * 32;         \
        const int ss_ = (2 * (t_) + (kh_)) & 3;                            \
        async_copy16(sa_,        ldsA + ss_ * 8192);                       \
        async_copy16(sa_ + a128, ldsA + ss_ * 8192 + 4096);                \
        async_copy16(sb_,        ldsB + ss_ * BSLOT);                      \
        async_copy16(sb_ + b128, ldsB + ss_ * BSLOT + 4096);               \
    } } while (0)

#define READS(AF_, AG_, BF_, SL_) do {                                         \
    _Pragma("unroll") for (int f = 0; f < 4; ++f)                              \
        (AF_)[f] = *(const f16x8*)(ldsArd + (SL_) * 16384 + f * 1024);         \
    _Pragma("unroll") for (int f = 0; f < 4; ++f)                              \
        (AG_)[f] = *(const f16x8*)(ldsArd + (SL_) * 16384 + f * 1024 + 4096);  \
    _Pragma("unroll") for (int f = 0; f < 4; ++f)                              \
        (BF_)[f] = *(const f16x8*)(ldsBrd + (SL_) * BSLOTB + f * 1024);        \
    } while (0)

#define MFMACL(AF_, AG_, BF_) do { __builtin_amdgcn_s_setprio(1);              \
    _Pragma("unroll") for (int f = 0; f < 4; ++f)                              \
    _Pragma("unroll") for (int nf = 0; nf < 4; ++nf)                           \
        acc[f][nf] = __builtin_amdgcn_mfma_f32_16x16x32_f16((AF_)[f], (BF_)[nf], acc[f][nf], 0, 0, 0); \
    _Pragma("unroll") for (int f = 0; f < 4; ++f)                              \
    _Pragma("unroll") for (int nf = 0; nf < 4; ++nf)                           \
        acc[4 + f][nf] = __builtin_amdgcn_mfma_f32_16x16x32_f16((AG_)[f], (BF_)[nf], acc[4 + f][nf], 0, 0, 0); \
    __builtin_amdgcn_s_setprio(0); } while (0)

        STG(0, 0); STG(0, 1); STG(1, 0);
        asm volatile("s_waitcnt vmcnt(4)" ::: "memory");
        __builtin_amdgcn_s_barrier();

        for (int T = 0; T < NT; ++T) {
            const int s0 = (2 * T) & 3;
            const int s1 = (2 * T + 1) & 3;
            f16x8 afA[4], agA[4], bfA[4];
            f16x8 afB[4], agB[4], bfB[4];
            READS(afA, agA, bfA, s0);
            STG(T + 1, 1);
            LGKM0();
            MFMACL(afA, agA, bfA);
            READS(afB, agB, bfB, s1);      // hoisted phase-B reads (s1 resident)
            __builtin_amdgcn_s_barrier();
            STG(T + 2, 0);
            LGKM0();
            MFMACL(afB, agB, bfB);
            if (T + 2 < NT) { asm volatile("s_waitcnt vmcnt(4)" ::: "memory"); }
            else            { asm volatile("s_waitcnt vmcnt(0)" ::: "memory"); }
            __builtin_amdgcn_s_barrier();
        }
#undef STG
#undef READS
#undef MFMACL
    } else {
        // ========= r16 single-phase loop (6-half-slot / 3-tile ring) =======
        // Stage one FULL K-tile (both halves, 6 loads) into slot pair ps_.
#define STG2(t_, ps_) do { if ((t_) < NT) {                                \
        const _Float16* sa_ = gA + (size_t)(t_) * 64;                      \
        const _Float16* sb_ = gB + (size_t)(t_) * 64;                      \
        async_copy16(sa_,             ldsA + (ps_) * 8192);                \
        async_copy16(sa_ + a128,      ldsA + (ps_) * 8192 + 4096);         \
        async_copy16(sb_,             ldsB + (ps_) * BSLOT);               \
        async_copy16(sa_ + 32,        ldsA + (ps_) * 8192 + 8192);         \
        async_copy16(sa_ + 32 + a128, ldsA + (ps_) * 8192 + 8192 + 4096);  \
        async_copy16(sb_ + 32,        ldsB + (ps_) * BSLOT + BSLOT);       \
    } } while (0)

        // prologue: tiles 0 -> slots {0,1}, 1 -> slots {2,3}; drain tile 0
        STG2(0, 0); STG2(1, 2);
        asm volatile("s_waitcnt vmcnt(6)" ::: "memory");
        __builtin_amdgcn_s_barrier();

        int pR = 0, pS = 4;
        for (int T = 0; T < NT; ++T) {
            f16x8 af0[4], bf0[4], af1[4], bf1[4];
            const int aO = pR * 16384;     // bytes: A half-slot = 16 KB
            const int bO = pR * BSLOTB;    // bytes: B half-slot = 8 KB
#pragma unroll
            for (int f = 0; f < 4; ++f)
                bf0[f] = *(const f16x8*)(ldsBrd + bO + f * 1024);
#pragma unroll
            for (int f = 0; f < 4; ++f)
                af0[f] = *(const f16x8*)(ldsArd + aO + f * 1024);
#pragma unroll
            for (int f = 0; f < 4; ++f)
                bf1[f] = *(const f16x8*)(ldsBrd + bO + BSLOTB + f * 1024);
#pragma unroll
            for (int f = 0; f < 4; ++f)
                af1[f] = *(const f16x8*)(ldsArd + aO + 16384 + f * 1024);
            STG2(T + 2, pS);   // targets tile T-1's slots: safe after BAR(T-1)
            LGKM0();
            __builtin_amdgcn_s_setprio(1);
#pragma unroll
            for (int f = 0; f < 4; ++f)
#pragma unroll
                for (int nf = 0; nf < 4; ++nf)
                    acc[f][nf] = __builtin_amdgcn_mfma_f32_16x16x32_f16(af0[f], bf0[nf], acc[f][nf], 0, 0, 0);
#pragma unroll
            for (int f = 0; f < 4; ++f)
#pragma unroll
                for (int nf = 0; nf < 4; ++nf)
                    acc[f][nf] = __builtin_amdgcn_mfma_f32_16x16x32_f16(af1[f], bf1[nf], acc[f][nf], 0, 0, 0);
            __builtin_amdgcn_s_setprio(0);
            if (T + 2 < NT) { asm volatile("s_waitcnt vmcnt(6)" ::: "memory"); }
            else            { asm volatile("s_waitcnt vmcnt(0)" ::: "memory"); }
            __builtin_amdgcn_s_barrier();
            pR += 2; if (pR == 6) pR = 0;
            pS += 2; if (pS == 6) pS = 0;
        }
#undef STG2
    }
#undef LGKM0

    // epilogue: C/D layout col = lane&15, row = (lane>>4)*4 + reg
    const int cn = lane & 15, rb4 = (lane >> 4) * 4;
    const int wmOff = (BN == 256) ? (w >> 2) * 128 : (w >> 1) * 64;
    const int wnOff = (BN == 256) ? (w & 3) * 64 : (w & 1) * 64;
#pragma unroll
    for (int i = 0; i < MR; ++i) {
        const int gm = m0 + wmOff + i * 16 + rb4;
#pragma unroll
        for (int j = 0; j < 4; ++j) {
            const int gn = n0 + wnOff + j * 16 + cn;
            const float bv = (MODE == 1) ? bias[gn] : 0.f;
#pragma unroll
            for (int r = 0; r < 4; ++r) {
                float v = acc[i][j][r] + bv;
                if (MODE == 1) v = v / (1.f + __expf(-v));
                C[(size_t)(gm + r) * ldc + gn] = (_Float16)v;
            }
        }
    }
}

// ---------------------------------------------------------------------------
// 128x128 m97-style GEMM for small shapes.
// MODE 0: silu(acc+bias+pre)->f16 (GEMM1', K=128).
// MODE 1: acc(+bias on z==0)->fp32 partial buffers, split-K via blockIdx.z.
// ---------------------------------------------------------------------------
template <int MODE>
__global__ __launch_bounds__(256)
void gemm_mfma(const _Float16* __restrict__ A0, int lda0,
               const _Float16* __restrict__ Bt, int ldb,
               const float* __restrict__ bias,
               const _Float16* __restrict__ preadd, int ldpre,
               _Float16* __restrict__ Hout,
               float* __restrict__ Fout,
               int N, int K)
{
    __shared__ __attribute__((aligned(16))) _Float16 As[128 * 64];
    __shared__ __attribute__((aligned(16))) _Float16 Bs[128 * 64];

    const int tid  = threadIdx.x;
    const int wave = tid >> 6;
    const int lane = tid & 63;
    const int m0 = blockIdx.y * 128;
    const int n0 = blockIdx.x * 128;
    const int wm = (wave >> 1) * 64;
    const int wn = (wave & 1) * 64;

    int kBeg = 0, kEnd = K;
    if (MODE == 1) {                   // split-K: z in {0,1}
        const int kh = K >> 1;
        kBeg = blockIdx.z * kh;
        kEnd = kBeg + kh;
        Fout += (size_t)blockIdx.z * BROWS * 256;
    }

    f32x4 acc[4][4];
#pragma unroll
    for (int i = 0; i < 4; ++i)
#pragma unroll
        for (int j = 0; j < 4; ++j)
            acc[i][j] = (f32x4){0.f, 0.f, 0.f, 0.f};

    const int rsub = lane >> 3;
    const int csub = ((lane & 7) ^ (lane >> 3)) * 8;

    for (int k0 = kBeg; k0 < kEnd; k0 += 64) {
#pragma unroll
        for (int i = 0; i < 4; ++i) {
            const int row = i * 32 + wave * 8 + rsub;
            async_copy16(A0 + (size_t)(m0 + row) * lda0 + k0 + csub,
                         &As[(i * 32 + wave * 8) * 64]);
        }
#pragma unroll
        for (int i = 0; i < 4; ++i) {
            const int row = i * 32 + wave * 8 + rsub;
            async_copy16(Bt + (size_t)(n0 + row) * ldb + k0 + csub,
                         &Bs[(i * 32 + wave * 8) * 64]);
        }
        __syncthreads();

#pragma unroll
        for (int kk = 0; kk < 2; ++kk) {
            const int c = ((kk * 4 + (lane >> 4)) ^ (lane & 7)) * 8;
            f16x8 af[4], bfr[4];
#pragma unroll
            for (int i = 0; i < 4; ++i) {
                af[i]  = *(const f16x8*)&As[(wm + i * 16 + (lane & 15)) * 64 + c];
                bfr[i] = *(const f16x8*)&Bs[(wn + i * 16 + (lane & 15)) * 64 + c];
            }
#pragma unroll
            for (int i = 0; i < 4; ++i)
#pragma unroll
                for (int j = 0; j < 4; ++j)
                    acc[i][j] = __builtin_amdgcn_mfma_f32_16x16x32_f16(af[i], bfr[j], acc[i][j], 0, 0, 0);
        }
        __syncthreads();
    }

    const int cn = lane & 15;
    const int rb = (lane >> 4) * 4;
#pragma unroll
    for (int j = 0; j < 4; ++j) {
        const int gn = n0 + wn + j * 16 + cn;
        const float bv = (MODE == 0 || blockIdx.z == 0) ? bias[gn] : 0.f;
#pragma unroll
        for (int i = 0; i < 4; ++i) {
            const int gm0 = m0 + wm + i * 16 + rb;
#pragma unroll
            for (int r = 0; r < 4; ++r) {
                float v = acc[i][j][r] + bv;
                if (MODE == 0) {
                    v += (float)preadd[(size_t)(gm0 + r) * ldpre + gn];
                    const float s = v / (1.f + __expf(-v));
                    Hout[(size_t)(gm0 + r) * N + gn] = (_Float16)s;
                } else {
                    Fout[(size_t)(gm0 + r) * N + gn] = v;
                }
            }
        }
    }
}

// ---------------------------------------------------------------------------
__global__ void transpose_to_f16(const float* __restrict__ in, _Float16* __restrict__ out,
                                 int K, int N, size_t inLayerStride, size_t outLayerStride)
{
    __shared__ float t[64][65];
    in  += (size_t)blockIdx.z * inLayerStride;
    out += (size_t)blockIdx.z * outLayerStride;
    const int kb = blockIdx.y * 64, nb = blockIdx.x * 64;
    const int tx = threadIdx.x & 63, ty = threadIdx.x >> 6;
#pragma unroll
    for (int i = 0; i < 64; i += 4)
        t[ty + i][tx] = in[(size_t)(kb + ty + i) * N + nb + tx];
    __syncthreads();
#pragma unroll
    for (int i = 0; i < 64; i += 4)
        out[(size_t)(nb + ty + i) * K + kb + tx] = (_Float16)t[tx][ty + i];
}

__global__ void build_cte(const float* __restrict__ ctx, const float* __restrict__ te,
                          const float* __restrict__ ce, _Float16* __restrict__ out)
{
    const int idx = blockIdx.x * blockDim.x + threadIdx.x;   // over B*768
    const int r = idx / (CTEDIM / 4);
    const int c = (idx % (CTEDIM / 4)) * 4;
    const float* src = (c < 1024) ? ctx + (size_t)r * 1024 + c
                     : (c < 2048) ? te  + (size_t)r * 1024 + (c - 1024)
                                  : ce  + (size_t)r * 1024 + (c - 2048);
    const float4 v = *reinterpret_cast<const float4*>(src);
    f16x4 o; o.x = (_Float16)v.x; o.y = (_Float16)v.y; o.z = (_Float16)v.z; o.w = (_Float16)v.w;
    *reinterpret_cast<f16x4*>(&out[idx * 4]) = o;
}

__global__ void build_biasSS(const float* __restrict__ bs, const float* __restrict__ bt,
                             float* __restrict__ out)
{
    const int id = blockIdx.x * 256 + threadIdx.x;   // L*256
    const int l = id >> 8, j = id & 255;
    out[id] = (j < 128) ? bs[l * 128 + j] : bt[l * 128 + (j - 128)];
}

__global__ void gather_xa0(const float* __restrict__ x, const int* __restrict__ perm,
                           const int* __restrict__ ia, _Float16* __restrict__ xa)
{
    const int r = blockIdx.x, j = threadIdx.x;   // 128 threads
    xa[(size_t)r * ADIM + j] = (_Float16)x[(size_t)r * DDIM + perm[ia[j]]];
}

// ---------------------------------------------------------------------------
// Coupling epilogue: 4 rows per 512-thread block; ss = ss0 + ss1 (split-K
// partials).  Fuses next layer's x_a gather.
// ---------------------------------------------------------------------------
__global__ __launch_bounds__(512)
void coupling_ep(const float* __restrict__ zin,
                 const float* __restrict__ ss0,
                 const float* __restrict__ ss1,
                 const int* __restrict__ perm,
                 const int* __restrict__ ia_,
                 const int* __restrict__ ib_,
                 const int* __restrict__ permN,
                 const int* __restrict__ iaN,
                 float* __restrict__ zout,
                 _Float16* __restrict__ xaN,
                 const float* __restrict__ ldin,
                 float* __restrict__ ldout,
                 int first)
{
    const int tid = threadIdx.x;
    const int r = blockIdx.x * 4 + (tid >> 7);   // 4 rows / block
    const int j = tid & 127;                     // j in [0,128)
    __shared__ float zrow[4][DDIM];
    __shared__ float part[8];                    // [row][wave-in-row]

    const int ia = ia_[j], ib = ib_[j];
    const float xav = zin[(size_t)r * DDIM + perm[ia]];
    const float xbv = zin[(size_t)r * DDIM + perm[ib]];
    float sc = ss0[(size_t)r * DDIM + j] + ss1[(size_t)r * DDIM + j];
    sc = fminf(CLIPV, fmaxf(-CLIPV, sc));
    const float sh = ss0[(size_t)r * DDIM + 128 + j] + ss1[(size_t)r * DDIM + 128 + j];
    const float yb = xbv * __expf(sc) + sh;

    const int rr4 = tid >> 7;
    zrow[rr4][ia] = xav;
    zrow[rr4][ib] = yb;

    float v = sc;
#pragma unroll
    for (int off = 32; off; off >>= 1) v += __shfl_down(v, off, 64);
    if ((tid & 63) == 0) part[tid >> 6] = v;
    __syncthreads();

    zout[(size_t)r * DDIM + j]       = zrow[rr4][j];
    zout[(size_t)r * DDIM + 128 + j] = zrow[rr4][128 + j];
    if (xaN) xaN[(size_t)r * ADIM + j] = (_Float16)zrow[rr4][permN[iaN[j]]];
    if (j == 0) ldout[r] = (first ? 0.f : ldin[r]) + part[rr4 * 2] + part[rr4 * 2 + 1];
}

// ---------------------------------------------------------------------------
extern "C" void kernel_launch(void* const* d_in, const int* in_sizes, int n_in,
                              void* d_out, int out_size, void* d_ws, size_t ws_size,
                              hipStream_t stream)
{
    const float* x    = (const float*)d_in[0];
    const float* ctx  = (const float*)d_in[1];
    const float* temb = (const float*)d_in[2];
    const float* cemb = (const float*)d_in[3];
    const float* W1   = (const float*)d_in[4];
    const float* b1   = (const float*)d_in[5];
    const float* W2   = (const float*)d_in[6];
    const float* b2   = (const float*)d_in[7];
    const float* W3   = (const float*)d_in[8];
    const float* b3   = (const float*)d_in[9];
    const float* Ws   = (const float*)d_in[10];
    const float* bs   = (const float*)d_in[11];
    const float* Wt   = (const float*)d_in[12];
    const float* bt   = (const float*)d_in[13];
    const int*   perm = (const int*)d_in[14];
    const int*   idxa = (const int*)d_in[15];
    const int*   idxb = (const int*)d_in[16];

    float* out_z  = (float*)d_out;
    float* out_ld = out_z + (size_t)BROWS * DDIM;

    // ---- workspace layout (lifetime-based aliasing) ----
    _Float16* W1at = (_Float16*)d_ws;                                 // 1 M f16
    _Float16* W2t  = W1at + (size_t)L_LAYERS * HDIM * ADIM;           // 8 M
    _Float16* W3t  = W2t  + (size_t)L_LAYERS * HDIM * HDIM;           // 8 M
    _Float16* WsWtT= W3t  + (size_t)L_LAYERS * HDIM * HDIM;           // 2 M
    _Float16* xa   = WsWtT+ (size_t)L_LAYERS * 256 * HDIM;            // 1 M
    _Float16* hB   = xa   + (size_t)BROWS * ADIM;                     // 8 M
    _Float16* pre  = hB   + (size_t)BROWS * HDIM;                     // 64 M
    float* biasSS  = (float*)(pre + (size_t)BROWS * L_LAYERS * HDIM); // 2 K f32
    // cte region (24 M f16): dead after big GEMM -> hA aliases it
    _Float16* cte  = (_Float16*)(biasSS + L_LAYERS * 256);
    _Float16* hA   = cte;
    // W1ct region (24 M f16): dead after big GEMM -> fp32 temporaries alias it
    _Float16* W1ct = cte + (size_t)BROWS * CTEDIM;
    float* ssbuf   = (float*)W1ct;                                    // 2 * B*256
    float* ssbuf2  = ssbuf + (size_t)BROWS * DDIM;
    float* z0      = ssbuf2 + (size_t)BROWS * DDIM;
    float* z1      = z0    + (size_t)BROWS * DDIM;
    float* ldacc   = z1    + (size_t)BROWS * DDIM;                    // B

    // ---- setup: weight transposes (fp32 -> f16, K x N -> N x K) ----
    transpose_to_f16<<<dim3(HDIM / 64, ADIM / 64, L_LAYERS), 256, 0, stream>>>(
        W1, W1at, ADIM, HDIM, (size_t)INDIM * HDIM, (size_t)HDIM * ADIM);
    transpose_to_f16<<<dim3(HDIM / 64, CTEDIM / 64, L_LAYERS), 256, 0, stream>>>(
        W1 + (size_t)ADIM * HDIM, W1ct, CTEDIM, HDIM,
        (size_t)INDIM * HDIM, (size_t)HDIM * CTEDIM);
    transpose_to_f16<<<dim3(HDIM / 64, HDIM / 64, L_LAYERS), 256, 0, stream>>>(
        W2, W2t, HDIM, HDIM, (size_t)HDIM * HDIM, (size_t)HDIM * HDIM);
    transpose_to_f16<<<dim3(HDIM / 64, HDIM / 64, L_LAYERS), 256, 0, stream>>>(
        W3, W3t, HDIM, HDIM, (size_t)HDIM * HDIM, (size_t)HDIM * HDIM);
    transpose_to_f16<<<dim3(BDIM_ / 64, HDIM / 64, L_LAYERS), 256, 0, stream>>>(
        Ws, WsWtT, HDIM, BDIM_, (size_t)HDIM * BDIM_, (size_t)256 * HDIM);
    transpose_to_f16<<<dim3(BDIM_ / 64, HDIM / 64, L_LAYERS), 256, 0, stream>>>(
        Wt, WsWtT + (size_t)BDIM_ * HDIM, HDIM, BDIM_, (size_t)HDIM * BDIM_, (size_t)256 * HDIM);

    build_cte<<<(BROWS * (CTEDIM / 4)) / 256, 256, 0, stream>>>(ctx, temb, cemb, cte);
    build_biasSS<<<L_LAYERS, 256, 0, stream>>>(bs, bt, biasSS);
    gather_xa0<<<BROWS, 128, 0, stream>>>(x, perm, idxa, xa);

    // ---- big layer-invariant GEMM: pre = cte @ W1c (grid 32x32, 16x8/XCD) --
    gemm8p<0, 256><<<dim3(1024), 512, 0, stream>>>(
        cte, CTEDIM, W1ct, CTEDIM, nullptr, pre, L_LAYERS * HDIM, CTEDIM,
        /*gx*/32, /*RC*/8, /*rr*/16);

    // ---- 8 coupling layers ----
    const float* zin = x;
    for (int l = 0; l < L_LAYERS; ++l) {
        const _Float16* w1a = W1at + (size_t)l * HDIM * ADIM;
        const _Float16* w2  = W2t  + (size_t)l * HDIM * HDIM;
        const _Float16* w3  = W3t  + (size_t)l * HDIM * HDIM;
        const _Float16* w4  = WsWtT+ (size_t)l * 256 * HDIM;

        // GEMM1': silu(xa @ W1a + pre[:, l*H:(l+1)*H] + b1) -> hA
        gemm_mfma<0><<<dim3(HDIM / 128, BROWS / 128), 256, 0, stream>>>(
            xa, ADIM, w1a, ADIM, b1 + (size_t)l * HDIM,
            pre + (size_t)l * HDIM, L_LAYERS * HDIM,
            hA, nullptr, HDIM, ADIM);
        // GEMM2: silu(hA @ W2 + b2) -> hB   (grid 32x8 = 256 wgs, 8x4/XCD)
        gemm8p<1, 128><<<dim3(256), 512, 0, stream>>>(
            hA, HDIM, w2, HDIM, b2 + (size_t)l * HDIM, hB, HDIM, HDIM,
            /*gx*/8, /*RC*/4, /*rr*/8);
        // GEMM3: silu(hB @ W3 + b3) -> hA
        gemm8p<1, 128><<<dim3(256), 512, 0, stream>>>(
            hB, HDIM, w3, HDIM, b3 + (size_t)l * HDIM, hA, HDIM, HDIM,
            /*gx*/8, /*RC*/4, /*rr*/8);
        // GEMM4: hA @ [Ws|Wt] + bias -> fp32 partials (split-K=2, 256 wgs)
        gemm_mfma<1><<<dim3(256 / 128, BROWS / 128, 2), 256, 0, stream>>>(
            hA, HDIM, w4, HDIM, biasSS + (size_t)l * 256,
            nullptr, 0, nullptr, ssbuf, 256, HDIM);

        // epilogue (4 rows / block, sums the two split-K partials)
        float* zout = (l == L_LAYERS - 1) ? out_z : ((l & 1) ? z1 : z0);
        const int last = (l == L_LAYERS - 1);
        coupling_ep<<<BROWS / 4, 512, 0, stream>>>(
            zin, ssbuf, ssbuf2,
            perm + (size_t)l * DDIM, idxa + (size_t)l * ADIM, idxb + (size_t)l * ADIM,
            last ? nullptr : perm + (size_t)(l + 1) * DDIM,
            last ? nullptr : idxa + (size_t)(l + 1) * ADIM,
            zout, last ? nullptr : xa,
            ldacc, last ? out_ld : ldacc, l == 0);
        zin = zout;
    }
}

// Round 17
// 1233.877 us; speedup vs baseline: 1.0220x; 1.0220x over previous
//
#include <hip/hip_runtime.h>

// ---------------------------------------------------------------------------
// ConditionalRealNVP on MI355X.  (Round-17 = revert to round-14 best: 1236us)
// Layer-invariant ctx-part of GEMM1 hoisted into ONE 8192x8192x3072 GEMM.
// Big GEMM + GEMM2/3: r13 template (one barrier per phase + hoisted phase-B
// ds_reads, counted vmcnt gate once per K-tile, pre-swizzled-source LDS,
// 2-D XCD regions).  GEMM4 split-K=2 (two fp32 partial buffers, 256 wgs);
// coupling_ep sums the partials, 4 rows per 512-thread block.
// ---------------------------------------------------------------------------

#define L_LAYERS 8
#define DDIM     256
#define HDIM     1024
#define BROWS    8192
#define ADIM     128          // D/2
#define BDIM_    128          // D - A
#define INDIM    3200         // A + 3*H
#define CTEDIM   3072         // 3*H
#define CLIPV    3.0f

typedef _Float16 f16x8 __attribute__((ext_vector_type(8)));
typedef _Float16 f16x4 __attribute__((ext_vector_type(4)));
typedef float    f32x4 __attribute__((ext_vector_type(4)));

__device__ __forceinline__ void async_copy16(const _Float16* g, _Float16* s) {
    __builtin_amdgcn_global_load_lds((const __attribute__((address_space(1))) void*)g,
                                     (__attribute__((address_space(3))) void*)s,
                                     16, 0, 0);
}

// ---------------------------------------------------------------------------
// 256xBN template GEMM: C = act(A @ Bt^T + bias)   (r13 structure)
// ---------------------------------------------------------------------------
template <int MODE, int BN>
__global__ __launch_bounds__(512, 2)
void gemm8p(const _Float16* __restrict__ A, int lda,
            const _Float16* __restrict__ Bt, int ldb,
            const float* __restrict__ bias,
            _Float16* __restrict__ C, int ldc,
            int K, int gx, int RC, int rr)
{
    constexpr int MR     = (BN == 256) ? 8 : 4;    // M fragments per wave
    constexpr int BSLOT  = BN * 32;                // f16 per B half-slot
    constexpr int BSLOTB = BN * 64;                // bytes per B half-slot
    __shared__ __attribute__((aligned(16))) _Float16 lds[32768 + 4 * BSLOT];

    const int tid  = threadIdx.x;
    const int w    = tid >> 6, lane = tid & 63;

    // ---- 2-D XCD region swizzle ----
    const int bid = blockIdx.x;
    const int xcd = bid & 7, idx = bid >> 3;
    const int rpx = gx / RC;
    const int by  = (xcd / rpx) * rr + idx / RC;
    const int bx  = (xcd % rpx) * RC + idx % RC;
    const int m0  = by << 8, n0 = bx * BN;

    const int NT = K >> 6;   // K-tiles; NT >= 4

    const int srow = tid >> 2;
    const int srcq = ((tid & 3) ^ ((tid >> 3) & 3)) * 8;
    const _Float16* gA = A  + (size_t)(m0 + srow) * lda + srcq;
    const _Float16* gB = Bt + (size_t)(n0 + srow) * ldb + srcq;
    const size_t a128 = (size_t)128 * lda;
    const size_t b128 = (size_t)128 * ldb;
    _Float16* ldsA = lds + w * 512;            // wave-uniform stage bases
    _Float16* ldsB = lds + 32768 + w * 512;

#define STG(t_, kh_) do { if ((t_) < NT) {                                 \
        const _Float16* sa_ = gA + (size_t)(t_) * 64 + (kh_) * 32;         \
        const _Float16* sb_ = gB + (size_t)(t_) * 64 + (kh_) * 32;         \
        const int ss_ = (2 * (t_) + (kh_)) & 3;                            \
        async_copy16(sa_,        ldsA + ss_ * 8192);                       \
        async_copy16(sa_ + a128, ldsA + ss_ * 8192 + 4096);                \
        async_copy16(sb_,        ldsB + ss_ * BSLOT);                      \
        if constexpr (BN == 256)                                           \
            async_copy16(sb_ + b128, ldsB + ss_ * BSLOT + 4096);           \
    } } while (0)

#define GATE_CNT() do {                                                    \
        if constexpr (BN == 256) { asm volatile("s_waitcnt vmcnt(4)" ::: "memory"); } \
        else                     { asm volatile("s_waitcnt vmcnt(3)" ::: "memory"); } \
    } while (0)

    f32x4 acc[MR][4];
#pragma unroll
    for (int i = 0; i < MR; ++i)
#pragma unroll
        for (int j = 0; j < 4; ++j) acc[i][j] = (f32x4){0.f, 0.f, 0.f, 0.f};

    // ---- prologue: stage g(0,0)->slot0, g(0,1)->slot1, g(1,0)->slot2 ----
    STG(0, 0); STG(0, 1); STG(1, 0);
    GATE_CNT();                         // drains g(0,0) AND g(0,1)
    __builtin_amdgcn_s_barrier();

    const int qsw = ((lane & 15) >> 1) & 3;
    const int q16 = ((lane >> 4) ^ qsw) << 4;
    const int rA0 = (BN == 256) ? ((w >> 2) * 128 + (lane & 15))
                                : ((w >> 1) * 64  + (lane & 15));
    const int rB  = (BN == 256) ? ((w & 3) * 64 + (lane & 15))
                                : ((w & 1) * 64 + (lane & 15));
    const char* ldsArd = (const char*)lds + (rA0 * 64 + q16);
    const char* ldsBrd = (const char*)lds + 65536 + (rB * 64 + q16);

#define READS(AF_, AG_, BF_, SL_) do {                                         \
    _Pragma("unroll") for (int f = 0; f < 4; ++f)                              \
        (BF_)[f] = *(const f16x8*)(ldsBrd + (SL_) * BSLOTB + f * 1024);        \
    _Pragma("unroll") for (int f = 0; f < 4; ++f)                              \
        (AF_)[f] = *(const f16x8*)(ldsArd + (SL_) * 16384 + f * 1024);         \
    if constexpr (BN == 256) {                                                 \
        _Pragma("unroll") for (int f = 0; f < 4; ++f)                          \
            (AG_)[f] = *(const f16x8*)(ldsArd + (SL_) * 16384 + f * 1024 + 4096); \
    } } while (0)

#define LGKM0() do { asm volatile("s_waitcnt lgkmcnt(0)" ::: "memory");        \
        __builtin_amdgcn_sched_barrier(0); } while (0)

#define MFMACL(AF_, AG_, BF_) do { __builtin_amdgcn_s_setprio(1);              \
    _Pragma("unroll") for (int f = 0; f < 4; ++f)                              \
    _Pragma("unroll") for (int nf = 0; nf < 4; ++nf)                           \
        acc[f][nf] = __builtin_amdgcn_mfma_f32_16x16x32_f16((AF_)[f], (BF_)[nf], acc[f][nf], 0, 0, 0); \
    if constexpr (BN == 256) {                                                 \
        _Pragma("unroll") for (int f = 0; f < 4; ++f)                          \
        _Pragma("unroll") for (int nf = 0; nf < 4; ++nf)                       \
            acc[4 + f][nf] = __builtin_amdgcn_mfma_f32_16x16x32_f16((AG_)[f], (BF_)[nf], acc[4 + f][nf], 0, 0, 0); \
    }                                                                          \
    __builtin_amdgcn_s_setprio(0); } while (0)

    for (int T = 0; T < NT; ++T) {
        const int s0 = (2 * T) & 3;
        const int s1 = (2 * T + 1) & 3;
        {
            f16x8 afA[4], agA[4], bfA[4];
            f16x8 afB[4], agB[4], bfB[4];
            READS(afA, agA, bfA, s0);
            STG(T + 1, 1);
            LGKM0();
            MFMACL(afA, agA, bfA);
            READS(afB, agB, bfB, s1);      // hoisted phase-B reads (s1 resident)
            __builtin_amdgcn_s_barrier();
            STG(T + 2, 0);
            LGKM0();
            MFMACL(afB, agB, bfB);
            if (T + 2 < NT) { GATE_CNT(); }
            else            { asm volatile("s_waitcnt vmcnt(0)" ::: "memory"); }
            __builtin_amdgcn_s_barrier();
        }
    }
#undef READS
#undef LGKM0
#undef MFMACL
#undef STG
#undef GATE_CNT

    const int cn = lane & 15, rb4 = (lane >> 4) * 4;
    const int wmOff = (BN == 256) ? (w >> 2) * 128 : (w >> 1) * 64;
    const int wnOff = (BN == 256) ? (w & 3) * 64 : (w & 1) * 64;
#pragma unroll
    for (int i = 0; i < MR; ++i) {
        const int gm = m0 + wmOff + i * 16 + rb4;
#pragma unroll
        for (int j = 0; j < 4; ++j) {
            const int gn = n0 + wnOff + j * 16 + cn;
            const float bv = (MODE == 1) ? bias[gn] : 0.f;
#pragma unroll
            for (int r = 0; r < 4; ++r) {
                float v = acc[i][j][r] + bv;
                if (MODE == 1) v = v / (1.f + __expf(-v));
                C[(size_t)(gm + r) * ldc + gn] = (_Float16)v;
            }
        }
    }
}

// ---------------------------------------------------------------------------
// 128x128 m97-style GEMM for small shapes.
// MODE 0: silu(acc+bias+pre)->f16 (GEMM1', K=128).
// MODE 1: acc(+bias on z==0)->fp32 partial buffers, split-K via blockIdx.z
//         (GEMM4: grid (2,64,2), each z does K/2; ep sums partials).
// ---------------------------------------------------------------------------
template <int MODE>
__global__ __launch_bounds__(256)
void gemm_mfma(const _Float16* __restrict__ A0, int lda0,
               const _Float16* __restrict__ Bt, int ldb,
               const float* __restrict__ bias,
               const _Float16* __restrict__ preadd, int ldpre,
               _Float16* __restrict__ Hout,
               float* __restrict__ Fout,
               int N, int K)
{
    __shared__ __attribute__((aligned(16))) _Float16 As[128 * 64];
    __shared__ __attribute__((aligned(16))) _Float16 Bs[128 * 64];

    const int tid  = threadIdx.x;
    const int wave = tid >> 6;
    const int lane = tid & 63;
    const int m0 = blockIdx.y * 128;
    const int n0 = blockIdx.x * 128;
    const int wm = (wave >> 1) * 64;
    const int wn = (wave & 1) * 64;

    int kBeg = 0, kEnd = K;
    if (MODE == 1) {                   // split-K: z in {0,1}
        const int kh = K >> 1;
        kBeg = blockIdx.z * kh;
        kEnd = kBeg + kh;
        Fout += (size_t)blockIdx.z * BROWS * 256;
    }

    f32x4 acc[4][4];
#pragma unroll
    for (int i = 0; i < 4; ++i)
#pragma unroll
        for (int j = 0; j < 4; ++j)
            acc[i][j] = (f32x4){0.f, 0.f, 0.f, 0.f};

    const int rsub = lane >> 3;
    const int csub = ((lane & 7) ^ (lane >> 3)) * 8;

    for (int k0 = kBeg; k0 < kEnd; k0 += 64) {
#pragma unroll
        for (int i = 0; i < 4; ++i) {
            const int row = i * 32 + wave * 8 + rsub;
            async_copy16(A0 + (size_t)(m0 + row) * lda0 + k0 + csub,
                         &As[(i * 32 + wave * 8) * 64]);
        }
#pragma unroll
        for (int i = 0; i < 4; ++i) {
            const int row = i * 32 + wave * 8 + rsub;
            async_copy16(Bt + (size_t)(n0 + row) * ldb + k0 + csub,
                         &Bs[(i * 32 + wave * 8) * 64]);
        }
        __syncthreads();

#pragma unroll
        for (int kk = 0; kk < 2; ++kk) {
            const int c = ((kk * 4 + (lane >> 4)) ^ (lane & 7)) * 8;
            f16x8 af[4], bfr[4];
#pragma unroll
            for (int i = 0; i < 4; ++i) {
                af[i]  = *(const f16x8*)&As[(wm + i * 16 + (lane & 15)) * 64 + c];
                bfr[i] = *(const f16x8*)&Bs[(wn + i * 16 + (lane & 15)) * 64 + c];
            }
#pragma unroll
            for (int i = 0; i < 4; ++i)
#pragma unroll
                for (int j = 0; j < 4; ++j)
                    acc[i][j] = __builtin_amdgcn_mfma_f32_16x16x32_f16(af[i], bfr[j], acc[i][j], 0, 0, 0);
        }
        __syncthreads();
    }

    const int cn = lane & 15;
    const int rb = (lane >> 4) * 4;
#pragma unroll
    for (int j = 0; j < 4; ++j) {
        const int gn = n0 + wn + j * 16 + cn;
        const float bv = (MODE == 0 || blockIdx.z == 0) ? bias[gn] : 0.f;
#pragma unroll
        for (int i = 0; i < 4; ++i) {
            const int gm0 = m0 + wm + i * 16 + rb;
#pragma unroll
            for (int r = 0; r < 4; ++r) {
                float v = acc[i][j][r] + bv;
                if (MODE == 0) {
                    v += (float)preadd[(size_t)(gm0 + r) * ldpre + gn];
                    const float s = v / (1.f + __expf(-v));
                    Hout[(size_t)(gm0 + r) * N + gn] = (_Float16)s;
                } else {
                    Fout[(size_t)(gm0 + r) * N + gn] = v;
                }
            }
        }
    }
}

// ---------------------------------------------------------------------------
__global__ void transpose_to_f16(const float* __restrict__ in, _Float16* __restrict__ out,
                                 int K, int N, size_t inLayerStride, size_t outLayerStride)
{
    __shared__ float t[64][65];
    in  += (size_t)blockIdx.z * inLayerStride;
    out += (size_t)blockIdx.z * outLayerStride;
    const int kb = blockIdx.y * 64, nb = blockIdx.x * 64;
    const int tx = threadIdx.x & 63, ty = threadIdx.x >> 6;
#pragma unroll
    for (int i = 0; i < 64; i += 4)
        t[ty + i][tx] = in[(size_t)(kb + ty + i) * N + nb + tx];
    __syncthreads();
#pragma unroll
    for (int i = 0; i < 64; i += 4)
        out[(size_t)(nb + ty + i) * K + kb + tx] = (_Float16)t[tx][ty + i];
}

__global__ void build_cte(const float* __restrict__ ctx, const float* __restrict__ te,
                          const float* __restrict__ ce, _Float16* __restrict__ out)
{
    const int idx = blockIdx.x * blockDim.x + threadIdx.x;   // over B*768
    const int r = idx / (CTEDIM / 4);
    const int c = (idx % (CTEDIM / 4)) * 4;
    const float* src = (c < 1024) ? ctx + (size_t)r * 1024 + c
                     : (c < 2048) ? te  + (size_t)r * 1024 + (c - 1024)
                                  : ce  + (size_t)r * 1024 + (c - 2048);
    const float4 v = *reinterpret_cast<const float4*>(src);
    f16x4 o; o.x = (_Float16)v.x; o.y = (_Float16)v.y; o.z = (_Float16)v.z; o.w = (_Float16)v.w;
    *reinterpret_cast<f16x4*>(&out[idx * 4]) = o;
}

__global__ void build_biasSS(const float* __restrict__ bs, const float* __restrict__ bt,
                             float* __restrict__ out)
{
    const int id = blockIdx.x * 256 + threadIdx.x;   // L*256
    const int l = id >> 8, j = id & 255;
    out[id] = (j < 128) ? bs[l * 128 + j] : bt[l * 128 + (j - 128)];
}

__global__ void gather_xa0(const float* __restrict__ x, const int* __restrict__ perm,
                           const int* __restrict__ ia, _Float16* __restrict__ xa)
{
    const int r = blockIdx.x, j = threadIdx.x;   // 128 threads
    xa[(size_t)r * ADIM + j] = (_Float16)x[(size_t)r * DDIM + perm[ia[j]]];
}

// ---------------------------------------------------------------------------
// Coupling epilogue: 4 rows per 512-thread block; ss = ss0 + ss1 (split-K
// partials).  Fuses next layer's x_a gather.
// ---------------------------------------------------------------------------
__global__ __launch_bounds__(512)
void coupling_ep(const float* __restrict__ zin,
                 const float* __restrict__ ss0,
                 const float* __restrict__ ss1,
                 const int* __restrict__ perm,
                 const int* __restrict__ ia_,
                 const int* __restrict__ ib_,
                 const int* __restrict__ permN,
                 const int* __restrict__ iaN,
                 float* __restrict__ zout,
                 _Float16* __restrict__ xaN,
                 const float* __restrict__ ldin,
                 float* __restrict__ ldout,
                 int first)
{
    const int tid = threadIdx.x;
    const int r = blockIdx.x * 4 + (tid >> 7);   // 4 rows / block
    const int j = tid & 127;                     // j in [0,128)
    __shared__ float zrow[4][DDIM];
    __shared__ float part[8];                    // [row][wave-in-row]

    const int ia = ia_[j], ib = ib_[j];
    const float xav = zin[(size_t)r * DDIM + perm[ia]];
    const float xbv = zin[(size_t)r * DDIM + perm[ib]];
    float sc = ss0[(size_t)r * DDIM + j] + ss1[(size_t)r * DDIM + j];
    sc = fminf(CLIPV, fmaxf(-CLIPV, sc));
    const float sh = ss0[(size_t)r * DDIM + 128 + j] + ss1[(size_t)r * DDIM + 128 + j];
    const float yb = xbv * __expf(sc) + sh;

    const int rr4 = tid >> 7;
    zrow[rr4][ia] = xav;
    zrow[rr4][ib] = yb;

    float v = sc;
#pragma unroll
    for (int off = 32; off; off >>= 1) v += __shfl_down(v, off, 64);
    if ((tid & 63) == 0) part[tid >> 6] = v;
    __syncthreads();

    zout[(size_t)r * DDIM + j]       = zrow[rr4][j];
    zout[(size_t)r * DDIM + 128 + j] = zrow[rr4][128 + j];
    if (xaN) xaN[(size_t)r * ADIM + j] = (_Float16)zrow[rr4][permN[iaN[j]]];
    if (j == 0) ldout[r] = (first ? 0.f : ldin[r]) + part[rr4 * 2] + part[rr4 * 2 + 1];
}

// ---------------------------------------------------------------------------
extern "C" void kernel_launch(void* const* d_in, const int* in_sizes, int n_in,
                              void* d_out, int out_size, void* d_ws, size_t ws_size,
                              hipStream_t stream)
{
    const float* x    = (const float*)d_in[0];
    const float* ctx  = (const float*)d_in[1];
    const float* temb = (const float*)d_in[2];
    const float* cemb = (const float*)d_in[3];
    const float* W1   = (const float*)d_in[4];
    const float* b1   = (const float*)d_in[5];
    const float* W2   = (const float*)d_in[6];
    const float* b2   = (const float*)d_in[7];
    const float* W3   = (const float*)d_in[8];
    const float* b3   = (const float*)d_in[9];
    const float* Ws   = (const float*)d_in[10];
    const float* bs   = (const float*)d_in[11];
    const float* Wt   = (const float*)d_in[12];
    const float* bt   = (const float*)d_in[13];
    const int*   perm = (const int*)d_in[14];
    const int*   idxa = (const int*)d_in[15];
    const int*   idxb = (const int*)d_in[16];

    float* out_z  = (float*)d_out;
    float* out_ld = out_z + (size_t)BROWS * DDIM;

    // ---- workspace layout (lifetime-based aliasing) ----
    _Float16* W1at = (_Float16*)d_ws;                                 // 1 M f16
    _Float16* W2t  = W1at + (size_t)L_LAYERS * HDIM * ADIM;           // 8 M
    _Float16* W3t  = W2t  + (size_t)L_LAYERS * HDIM * HDIM;           // 8 M
    _Float16* WsWtT= W3t  + (size_t)L_LAYERS * HDIM * HDIM;           // 2 M
    _Float16* xa   = WsWtT+ (size_t)L_LAYERS * 256 * HDIM;            // 1 M
    _Float16* hB   = xa   + (size_t)BROWS * ADIM;                     // 8 M
    _Float16* pre  = hB   + (size_t)BROWS * HDIM;                     // 64 M
    float* biasSS  = (float*)(pre + (size_t)BROWS * L_LAYERS * HDIM); // 2 K f32
    // cte region (24 M f16): dead after big GEMM -> hA aliases it
    _Float16* cte  = (_Float16*)(biasSS + L_LAYERS * 256);
    _Float16* hA   = cte;
    // W1ct region (24 M f16): dead after big GEMM -> fp32 temporaries alias it
    _Float16* W1ct = cte + (size_t)BROWS * CTEDIM;
    float* ssbuf   = (float*)W1ct;                                    // 2 * B*256
    float* ssbuf2  = ssbuf + (size_t)BROWS * DDIM;
    float* z0      = ssbuf2 + (size_t)BROWS * DDIM;
    float* z1      = z0    + (size_t)BROWS * DDIM;
    float* ldacc   = z1    + (size_t)BROWS * DDIM;                    // B

    // ---- setup: weight transposes (fp32 -> f16, K x N -> N x K) ----
    transpose_to_f16<<<dim3(HDIM / 64, ADIM / 64, L_LAYERS), 256, 0, stream>>>(
        W1, W1at, ADIM, HDIM, (size_t)INDIM * HDIM, (size_t)HDIM * ADIM);
    transpose_to_f16<<<dim3(HDIM / 64, CTEDIM / 64, L_LAYERS), 256, 0, stream>>>(
        W1 + (size_t)ADIM * HDIM, W1ct, CTEDIM, HDIM,
        (size_t)INDIM * HDIM, (size_t)HDIM * CTEDIM);
    transpose_to_f16<<<dim3(HDIM / 64, HDIM / 64, L_LAYERS), 256, 0, stream>>>(
        W2, W2t, HDIM, HDIM, (size_t)HDIM * HDIM, (size_t)HDIM * HDIM);
    transpose_to_f16<<<dim3(HDIM / 64, HDIM / 64, L_LAYERS), 256, 0, stream>>>(
        W3, W3t, HDIM, HDIM, (size_t)HDIM * HDIM, (size_t)HDIM * HDIM);
    transpose_to_f16<<<dim3(BDIM_ / 64, HDIM / 64, L_LAYERS), 256, 0, stream>>>(
        Ws, WsWtT, HDIM, BDIM_, (size_t)HDIM * BDIM_, (size_t)256 * HDIM);
    transpose_to_f16<<<dim3(BDIM_ / 64, HDIM / 64, L_LAYERS), 256, 0, stream>>>(
        Wt, WsWtT + (size_t)BDIM_ * HDIM, HDIM, BDIM_, (size_t)HDIM * BDIM_, (size_t)256 * HDIM);

    build_cte<<<(BROWS * (CTEDIM / 4)) / 256, 256, 0, stream>>>(ctx, temb, cemb, cte);
    build_biasSS<<<L_LAYERS, 256, 0, stream>>>(bs, bt, biasSS);
    gather_xa0<<<BROWS, 128, 0, stream>>>(x, perm, idxa, xa);

    // ---- big layer-invariant GEMM: pre = cte @ W1c (grid 32x32, 16x8/XCD) --
    gemm8p<0, 256><<<dim3(1024), 512, 0, stream>>>(
        cte, CTEDIM, W1ct, CTEDIM, nullptr, pre, L_LAYERS * HDIM, CTEDIM,
        /*gx*/32, /*RC*/8, /*rr*/16);

    // ---- 8 coupling layers ----
    const float* zin = x;
    for (int l = 0; l < L_LAYERS; ++l) {
        const _Float16* w1a = W1at + (size_t)l * HDIM * ADIM;
        const _Float16* w2  = W2t  + (size_t)l * HDIM * HDIM;
        const _Float16* w3  = W3t  + (size_t)l * HDIM * HDIM;
        const _Float16* w4  = WsWtT+ (size_t)l * 256 * HDIM;

        // GEMM1': silu(xa @ W1a + pre[:, l*H:(l+1)*H] + b1) -> hA
        gemm_mfma<0><<<dim3(HDIM / 128, BROWS / 128), 256, 0, stream>>>(
            xa, ADIM, w1a, ADIM, b1 + (size_t)l * HDIM,
            pre + (size_t)l * HDIM, L_LAYERS * HDIM,
            hA, nullptr, HDIM, ADIM);
        // GEMM2: silu(hA @ W2 + b2) -> hB   (grid 32x8 = 256 wgs, 8x4/XCD)
        gemm8p<1, 128><<<dim3(256), 512, 0, stream>>>(
            hA, HDIM, w2, HDIM, b2 + (size_t)l * HDIM, hB, HDIM, HDIM,
            /*gx*/8, /*RC*/4, /*rr*/8);
        // GEMM3: silu(hB @ W3 + b3) -> hA
        gemm8p<1, 128><<<dim3(256), 512, 0, stream>>>(
            hB, HDIM, w3, HDIM, b3 + (size_t)l * HDIM, hA, HDIM, HDIM,
            /*gx*/8, /*RC*/4, /*rr*/8);
        // GEMM4: hA @ [Ws|Wt] + bias -> fp32 partials (split-K=2, 256 wgs)
        gemm_mfma<1><<<dim3(256 / 128, BROWS / 128, 2), 256, 0, stream>>>(
            hA, HDIM, w4, HDIM, biasSS + (size_t)l * 256,
            nullptr, 0, nullptr, ssbuf, 256, HDIM);

        // epilogue (4 rows / block, sums the two split-K partials)
        float* zout = (l == L_LAYERS - 1) ? out_z : ((l & 1) ? z1 : z0);
        const int last = (l == L_LAYERS - 1);
        coupling_ep<<<BROWS / 4, 512, 0, stream>>>(
            zin, ssbuf, ssbuf2,
            perm + (size_t)l * DDIM, idxa + (size_t)l * ADIM, idxb + (size_t)l * ADIM,
            last ? nullptr : perm + (size_t)(l + 1) * DDIM,
            last ? nullptr : idxa + (size_t)(l + 1) * ADIM,
            zout, last ? nullptr : xa,
            ldacc, last ? out_ld : ldacc, l == 0);
        zin = zout;
    }
}